// Round 4
// baseline (228.379 us; speedup 1.0000x reference)
//
#include <hip/hip_runtime.h>

typedef unsigned short u16;
typedef __bf16 bf16x8 __attribute__((ext_vector_type(8)));
typedef float f32x4 __attribute__((ext_vector_type(4)));
typedef unsigned short u16x8 __attribute__((ext_vector_type(8)));

#define F_FACES 65536
#define N_FACES 131072
#define C_CH 128
// ws layout (bytes):
//   [0,256)        zeropage (zeros; masked-gather target)
//   [256,3328)     W2 folded fp32  [b][o][i]  (768 floats)
//   [3328,4352)    (unused; was styles1)
//   [4352,5376)    (unused; was styles2)
//   [5376,595200)  W1 folded bf16, FRAGMENT layout [b][k][chunk16][o128][j8]
//   [595200, +16777216) const bf16 copy [F][C]
#define WS_W2F 256
#define WS_W1 5376
#define WS_CONST 595200
#define XELEMS 16777216  // N_FACES*128

__device__ inline u16 f2bf(float f) {
    unsigned u = __builtin_bit_cast(unsigned, f);
    unsigned r = (u + 0x7fffu + ((u >> 16) & 1u)) >> 16;
    return (u16)r;
}

__device__ inline void gl_lds16(const void* g, void* l) {
    __builtin_amdgcn_global_load_lds(
        (const __attribute__((address_space(1))) void*)g,
        (__attribute__((address_space(3))) void*)l, 16, 0, 0);
}

// nontemporal 16B load via ext-vector (HIP float4 is a struct -> builtin rejects it)
__device__ inline f32x4 nt_load4(const float* p) {
    return __builtin_nontemporal_load((const f32x4*)p);
}

// ---------------- kernel 0: fused {W1 styles+demod+fold | W2 styles+fold | const cvt}
// blocks [0,256): per-(b,o): compute styles1[b][:] in-block, demod, fold W1 fragments
// block 256: compute styles2 in-block, W2 fold + zeropage
// blocks [257,4353): fp32->bf16 const copy (nontemporal reads -- read-once stream)
__global__ __launch_bounds__(256) void k0_all(
    const float* __restrict__ wsv, const float* __restrict__ a1W, const float* __restrict__ a1b,
    const float* __restrict__ a2W, const float* __restrict__ a2b,
    const float* __restrict__ cst, const float* __restrict__ w1g,
    const float* __restrict__ w2, unsigned char* __restrict__ wsb)
{
    __shared__ float part[2][128];
    __shared__ float s1sh[128];
    __shared__ float red[4];
    int bid = blockIdx.x;
    int tid = threadIdx.x;

    if (bid >= 257) {
        // const fp32 -> bf16 table copy
        u16* dst = (u16*)(wsb + WS_CONST);
        int base = ((bid - 257) * 256 + tid) * 8;
        f32x4 a = nt_load4(cst + base);
        f32x4 c = nt_load4(cst + base + 4);
        u16x8 p;
        p[0] = f2bf(a[0]); p[1] = f2bf(a[1]); p[2] = f2bf(a[2]); p[3] = f2bf(a[3]);
        p[4] = f2bf(c[0]); p[5] = f2bf(c[1]); p[6] = f2bf(c[2]); p[7] = f2bf(c[3]);
        *(u16x8*)(dst + base) = p;
        return;
    }
    const float g512 = 0.04419417382415922f;   // 1/sqrt(512)
    const float g128 = 0.08838834764831845f;   // 1/sqrt(128)
    if (bid < 256) {
        // ---- W1 demod + fold for (b,o); styles1 computed locally ----
        int b = bid >> 7, o = bid & 127;
        int h = tid >> 7, i = tid & 127;
        {
            const float4* xr = (const float4*)(wsv + (size_t)(b * 2 + 0) * 512) + h * 64;
            const float4* ar = (const float4*)(a1W + (size_t)i * 512) + h * 64;
            float p = 0.f;
#pragma unroll 8
            for (int j = 0; j < 64; ++j) {
                float4 w4 = ar[j], x4 = xr[j];
                p += w4.x * x4.x + w4.y * x4.y + w4.z * x4.z + w4.w * x4.w;
            }
            part[h][i] = p;
        }
        __syncthreads();
        if (tid < 128) s1sh[tid] = (part[0][tid] + part[1][tid]) * g512 + a1b[tid];
        __syncthreads();
        float sum = 0.f;
        for (int e = tid; e < 1152; e += 256) {
            int ii = e / 9;
            float w = w1g[(size_t)o * 1152 + e] * s1sh[ii];
            sum += w * w;
        }
        int wv = tid >> 6, lane = tid & 63;
#pragma unroll
        for (int d = 1; d < 64; d <<= 1) sum += __shfl_xor(sum, d);
        if (lane == 0) red[wv] = sum;
        __syncthreads();
        float dm = rsqrtf(red[0] + red[1] + red[2] + red[3] + 1e-8f);
        u16* w1out = (u16*)(wsb + WS_W1);
        for (int wd = tid; wd < 576; wd += 256) {
            int k = wd >> 6;
            int ii = (wd & 63) * 2;
            float v0 = w1g[((size_t)o * 128 + ii) * 9 + k] * s1sh[ii] * dm;
            float v1 = w1g[((size_t)o * 128 + ii + 1) * 9 + k] * s1sh[ii + 1] * dm;
            unsigned pack = (unsigned)f2bf(v0) | ((unsigned)f2bf(v1) << 16);
            *(unsigned*)&w1out[(size_t)((((b * 9 + k) * 16 + (ii >> 3)) * 128 + o) * 8 + (ii & 7))] = pack;
        }
        return;
    }
    // ---- bid == 256: styles2 in-block + zeropage + W2 fold ----
    {
        float* s2sh = &part[0][0];  // reuse 256 floats of LDS
        int b = tid >> 7, i = tid & 127;
        const float4* xr = (const float4*)(wsv + (size_t)(b * 2 + 1) * 512);
        const float4* ar = (const float4*)(a2W + (size_t)i * 512);
        float p = 0.f;
#pragma unroll 8
        for (int j = 0; j < 128; ++j) {
            float4 w4 = ar[j], x4 = xr[j];
            p += w4.x * x4.x + w4.y * x4.y + w4.z * x4.z + w4.w * x4.w;
        }
        s2sh[tid] = (p * g512 + a2b[i]) * g128;
        __syncthreads();
        float* wsf = (float*)wsb;
        if (tid < 64) wsf[tid] = 0.f;
#pragma unroll
        for (int r = 0; r < 3; ++r) {
            int id = tid + r * 256;  // < 768
            int b2 = id / 384;
            int rem = id - b2 * 384;
            int o2 = rem >> 7;
            int ii = rem & 127;
            wsf[WS_W2F / 4 + id] = w2[o2 * 128 + ii] * s2sh[b2 * 128 + ii];
        }
    }
}

// ---------------- kernel 1: gathered GEMM conv1, double-buffered + counted vmcnt ----
// 256 threads (4 waves), 64x128 tile, LDS 2x16KB. Structure unchanged from R2
// (BW-pinned); only change: nontemporal stores on out (no write-allocate RFO,
// no L2 pollution of the gather table).
__global__ __launch_bounds__(256, 5) void k1_conv(
    const int* __restrict__ neigh, const int* __restrict__ ispad,
    const float* __restrict__ noise_c, const float* __restrict__ nstr,
    const float* __restrict__ bias1, const unsigned char* __restrict__ wsb,
    float* __restrict__ out)
{
    __shared__ __align__(16) u16 As[2][64 * 128];  // 2x16KB double buffer, XOR-16 swizzled

    const int tid = threadIdx.x;
    const int wv = tid >> 6, lane = tid & 63;
    const int quad = lane >> 4, l15 = lane & 15;
    const int f0 = blockIdx.x * 64;
    const int b = f0 >> 16;
    const u16* cst = (const u16*)(wsb + WS_CONST);
    const u16* w1ws = (const u16*)(wsb + WS_W1) + (size_t)b * 147456;  // 9*16*128*8
    const char* zp = (const char*)wsb;

    f32x4 acc[4][2] = {};
    int ia[4], ip[4];

    // ---- prologue: idx(0), stage tile0 -> buf0, idx(1) ----
#pragma unroll
    for (int r = 0; r < 4; ++r) {
        int nb = (f0 + (wv * 4 + r) * 4 + quad) * 9 + 0;
        ia[r] = neigh[nb]; ip[r] = ispad[nb];
    }
#pragma unroll
    for (int r = 0; r < 4; ++r) {
        int row = (wv * 4 + r) * 4 + quad;
        bool valid = (ip[r] == 0) && ((unsigned)ia[r] < 131072u);
        const char* src = valid ? (const char*)(cst + ((size_t)(ia[r] & 65535) << 7)) : zp;
        gl_lds16(src + ((l15 ^ (row & 15)) << 4), (char*)(&As[0][0]) + ((wv * 4 + r) << 10));
    }
#pragma unroll
    for (int r = 0; r < 4; ++r) {
        int nb = (f0 + (wv * 4 + r) * 4 + quad) * 9 + 1;
        ia[r] = neigh[nb]; ip[r] = ispad[nb];
    }

#pragma unroll
    for (int k = 0; k < 9; ++k) {
        // B fragments for this k — issued FIRST so consuming them in compute
        // does not FIFO-drain the k+1 gather prefetch.
        bf16x8 bfr[4][2];
#pragma unroll
        for (int s = 0; s < 4; ++s)
#pragma unroll
            for (int nt = 0; nt < 2; ++nt)
                bfr[s][nt] = *reinterpret_cast<const bf16x8*>(
                    w1ws + (((k * 16 + s * 4 + quad) * 128) + wv * 32 + nt * 16 + l15) * 8);
        asm volatile("" ::: "memory");
        __builtin_amdgcn_sched_barrier(0);

        // stage tile k+1 (gather, masked -> zeropage), swizzled source
        if (k < 8) {
#pragma unroll
            for (int r = 0; r < 4; ++r) {
                int row = (wv * 4 + r) * 4 + quad;
                bool valid = (ip[r] == 0) && ((unsigned)ia[r] < 131072u);
                const char* src = valid ? (const char*)(cst + ((size_t)(ia[r] & 65535) << 7)) : zp;
                gl_lds16(src + ((l15 ^ (row & 15)) << 4),
                         (char*)(&As[(k + 1) & 1][0]) + ((wv * 4 + r) << 10));
            }
        }
        // prefetch neighbor indices for tile k+2 (consumed next iteration -> wait is free)
        if (k < 7) {
#pragma unroll
            for (int r = 0; r < 4; ++r) {
                int nb = (f0 + (wv * 4 + r) * 4 + quad) * 9 + (k + 2);
                ia[r] = neigh[nb]; ip[r] = ispad[nb];
            }
        }
        // counted vmcnt: N = ops issued after tile-k's gathers (8 B + 4 gl_lds + 8 idx)
        if (k < 7)       asm volatile("s_waitcnt vmcnt(20)" ::: "memory");
        else if (k == 7) asm volatile("s_waitcnt vmcnt(12)" ::: "memory");
        else             asm volatile("s_waitcnt vmcnt(8)" ::: "memory");
        __builtin_amdgcn_s_barrier();
        __builtin_amdgcn_sched_barrier(0);

        // compute on As[k&1]
        const u16* Ab = &As[k & 1][0];
#pragma unroll
        for (int s = 0; s < 4; ++s) {
            bf16x8 af[4];
#pragma unroll
            for (int mt = 0; mt < 4; ++mt) {
                int face = mt * 16 + l15;
                int chunk = (s * 4 + quad) ^ l15;
                af[mt] = *reinterpret_cast<const bf16x8*>(&Ab[face * 128 + chunk * 8]);
            }
#pragma unroll
            for (int mt = 0; mt < 4; ++mt)
#pragma unroll
                for (int nt = 0; nt < 2; ++nt)
                    acc[mt][nt] = __builtin_amdgcn_mfma_f32_16x16x32_bf16(
                        af[mt], bfr[s][nt], acc[mt][nt], 0, 0, 0);
        }
        asm volatile("s_waitcnt lgkmcnt(0)" ::: "memory");
        __builtin_amdgcn_s_barrier();
        __builtin_amdgcn_sched_barrier(0);
    }

    // epilogue: + noise + bias1, lrelu(0.2)*sqrt(2), clip +-256, nontemporal fp32 store
    float ns = nstr[0];
    float b1v[2];
    b1v[0] = bias1[wv * 32 + l15];
    b1v[1] = bias1[wv * 32 + 16 + l15];
#pragma unroll
    for (int mt = 0; mt < 4; ++mt) {
#pragma unroll
        for (int r = 0; r < 4; ++r) {
            int face = f0 + mt * 16 + quad * 4 + r;
            float nz = noise_c[face & 65535] * ns;
#pragma unroll
            for (int nt = 0; nt < 2; ++nt) {
                float v = acc[mt][nt][r] + nz + b1v[nt];
                v = (v > 0.f) ? v : 0.2f * v;
                v *= 1.41421356f;
                v = fminf(fmaxf(v, -256.f), 256.f);
                __builtin_nontemporal_store(v, &out[(size_t)face * 128 + wv * 32 + nt * 16 + l15]);
            }
        }
    }
}

// ---------------- kernel 2: conv2 (k=1 gather) + bias + clip ----------------
// No LDS / no barrier: weights (3KB, L2-hot) read directly; x read-once ->
// nontemporal loads; tiny img store nontemporal.
__global__ __launch_bounds__(256) void k2_img(
    const int* __restrict__ neigh, const int* __restrict__ ispad,
    const float* __restrict__ w2f, const float* __restrict__ bias2,
    const float* __restrict__ xbuf, float* __restrict__ imgout)
{
    int tid = threadIdx.x;
    int wv = tid >> 6, lane = tid & 63;
    int g = lane >> 4, sub = lane & 15;
    int face = blockIdx.x * 16 + wv * 4 + g;
    int b = face >> 16;
    int idx = neigh[face * 9];
    bool valid = (ispad[face * 9] == 0) && ((unsigned)idx < 131072u);
    float a0 = 0.f, a1 = 0.f, a2 = 0.f;
    if (valid) {
        const float* xr = xbuf + (size_t)idx * 128 + sub * 8;
        f32x4 d0 = nt_load4(xr);
        f32x4 d1 = nt_load4(xr + 4);
        const float4* w04 = (const float4*)(w2f + (b * 3 + 0) * 128 + sub * 8);
        const float4* w14 = (const float4*)(w2f + (b * 3 + 1) * 128 + sub * 8);
        const float4* w24 = (const float4*)(w2f + (b * 3 + 2) * 128 + sub * 8);
        float4 w0a = w04[0], w0b = w04[1];
        float4 w1a = w14[0], w1b = w14[1];
        float4 w2a = w24[0], w2b = w24[1];
        a0 = d0[0] * w0a.x + d0[1] * w0a.y + d0[2] * w0a.z + d0[3] * w0a.w
           + d1[0] * w0b.x + d1[1] * w0b.y + d1[2] * w0b.z + d1[3] * w0b.w;
        a1 = d0[0] * w1a.x + d0[1] * w1a.y + d0[2] * w1a.z + d0[3] * w1a.w
           + d1[0] * w1b.x + d1[1] * w1b.y + d1[2] * w1b.z + d1[3] * w1b.w;
        a2 = d0[0] * w2a.x + d0[1] * w2a.y + d0[2] * w2a.z + d0[3] * w2a.w
           + d1[0] * w2b.x + d1[1] * w2b.y + d1[2] * w2b.z + d1[3] * w2b.w;
    }
#pragma unroll
    for (int d = 1; d < 16; d <<= 1) {
        a0 += __shfl_xor(a0, d);
        a1 += __shfl_xor(a1, d);
        a2 += __shfl_xor(a2, d);
    }
    if (sub < 3) {
        float v = (sub == 0) ? a0 : (sub == 1) ? a1 : a2;
        v += bias2[sub];
        v = fminf(fmaxf(v, -256.f), 256.f);
        __builtin_nontemporal_store(v, &imgout[face * 3 + sub]);
    }
}

extern "C" void kernel_launch(void* const* d_in, const int* in_sizes, int n_in,
                              void* d_out, int out_size, void* d_ws, size_t ws_size,
                              hipStream_t stream) {
    const int* neigh = (const int*)d_in[0];
    const int* ispad = (const int*)d_in[1];
    const float* wsv = (const float*)d_in[2];
    const float* cst = (const float*)d_in[3];
    const float* a1W = (const float*)d_in[4];
    const float* a1b = (const float*)d_in[5];
    const float* w1g = (const float*)d_in[6];
    const float* noise_c = (const float*)d_in[7];
    const float* nstr = (const float*)d_in[8];
    const float* bias1 = (const float*)d_in[9];
    const float* a2W = (const float*)d_in[10];
    const float* a2b = (const float*)d_in[11];
    const float* w2 = (const float*)d_in[12];
    const float* bias2 = (const float*)d_in[13];
    float* out = (float*)d_out;
    unsigned char* wsb = (unsigned char*)d_ws;

    k0_all<<<4353, 256, 0, stream>>>(wsv, a1W, a1b, a2W, a2b, cst, w1g, w2, wsb);
    k1_conv<<<2048, 256, 0, stream>>>(neigh, ispad, noise_c, nstr, bias1, wsb, out);
    k2_img<<<8192, 256, 0, stream>>>(neigh, ispad, (const float*)(wsb + WS_W2F), bias2,
                                     out, out + XELEMS);
}